// Round 14
// baseline (78.707 us; speedup 1.0000x reference)
//
#include <hip/hip_runtime.h>
#include <cstdint>
#include <cstddef>

#define NEG_SLOPE 0.2f
#define LOG2E 1.4426950408889634f

// Problem sizes (fixed by setup_inputs)
#define BB 2
#define NN 2048
#define DD 512
#define HH 8
#define KK 64   // head dim

typedef _Float16 half8 __attribute__((ext_vector_type(8)));
typedef _Float16 half4 __attribute__((ext_vector_type(4)));
typedef _Float16 half2v __attribute__((ext_vector_type(2)));
typedef float floatx4 __attribute__((ext_vector_type(4)));

// Workspace layout (bytes)
#define X16T_OFF  ((size_t)0)            // x16 tiled: [256 mtile][64 chunk][16 m][8 k] f16 = 4 MB
#define WT_OFF    ((size_t)4194304)      // WT[o][d] f16 = 512 KB
#define XHT_OFF   ((size_t)4718592)      // xhT2: [B*H][32 c][64 kk][64 j] f16 (plain) = 4 MB
#define ASRC_OFF  ((size_t)8912896)      // 32768 f32 = 128 KB
#define AFP_OFF   ((size_t)9043968)      // aFp: [bh][n/2] u32 (F+ pairs) = 64 KB
#define AFM_OFF   ((size_t)9109504)      // aFm: [bh][n/2] u32 (F- pairs) = 64 KB
#define ADMAX_OFF ((size_t)9175040)      // [16 bh][128] f32 = 8 KB
#define MW_OFF    ((size_t)9183232)      // mwT: [B][32][2048] u64 = 1 MB

// packed pair op: max(Ep2*fp, Em2*fm) elementwise on 2 f16 halves
__device__ __forceinline__ unsigned pkmm(unsigned Ep2, unsigned fp,
                                         unsigned Em2, unsigned fm) {
    union U { unsigned u; half2v h; };
    U a, b, c, d, r;
    a.u = Ep2; b.u = fp; c.u = Em2; d.u = fm;
    r.h = __builtin_elementwise_max(a.h * b.h, c.h * d.h);
    return r.u;
}

// ---------------- Kernel 0: x->f16 tiled + W transpose->f16 -------------------
__global__ __launch_bounds__(256) void k_prep(const float* __restrict__ x,
                                              const float* __restrict__ Wp,
                                              _Float16* __restrict__ x16t,
                                              _Float16* __restrict__ WT) {
    __shared__ float tile[64][65];
    const int tid = threadIdx.x;
    const int bi = blockIdx.x;
    if (bi < 256) {                       // x conversion to tiled layout
        const int r = tid & 15, cg = tid >> 4;
        const float* srow = x + (size_t)(bi * 16 + r) * DD;
        _Float16* obase = x16t + ((size_t)bi * 64) * 128 + r * 8;
#pragma unroll
        for (int q = 0; q < 4; ++q) {
            const int chunk = q * 16 + cg;
            float4 v0 = *(const float4*)(srow + chunk * 8);
            float4 v1 = *(const float4*)(srow + chunk * 8 + 4);
            half8 hv;
            hv[0] = (_Float16)v0.x; hv[1] = (_Float16)v0.y;
            hv[2] = (_Float16)v0.z; hv[3] = (_Float16)v0.w;
            hv[4] = (_Float16)v1.x; hv[5] = (_Float16)v1.y;
            hv[6] = (_Float16)v1.z; hv[7] = (_Float16)v1.w;
            *(half8*)(obase + (size_t)chunk * 128) = hv;
        }
    } else {                              // W transpose: 64 blocks of 64x64
        const int wb = bi - 256;
        const int d0 = (wb >> 3) * 64, o0 = (wb & 7) * 64;
        const int r = tid >> 2, cq = tid & 3;
#pragma unroll
        for (int qq = 0; qq < 4; ++qq) {
            float4 v = *(const float4*)&Wp[(size_t)(d0 + r) * DD + o0 + cq * 16 + qq * 4];
            tile[r][cq * 16 + qq * 4 + 0] = v.x;
            tile[r][cq * 16 + qq * 4 + 1] = v.y;
            tile[r][cq * 16 + qq * 4 + 2] = v.z;
            tile[r][cq * 16 + qq * 4 + 3] = v.w;
        }
        __syncthreads();
#pragma unroll
        for (int qq = 0; qq < 2; ++qq) {
            half8 hv;
#pragma unroll
            for (int e = 0; e < 8; ++e) hv[e] = (_Float16)tile[cq * 16 + qq * 8 + e][r];
            *(half8*)&WT[(size_t)(o0 + r) * DD + d0 + cq * 16 + qq * 8] = hv;
        }
    }
}

// ---------------- Kernel 1: FUSED mask pack (1024 blk) + proj GEMM (512 blk) --
__global__ __launch_bounds__(256) void k_pj(const int* __restrict__ A,
                                            const _Float16* __restrict__ x16t,
                                            const _Float16* __restrict__ WT,
                                            const float* __restrict__ Watt,
                                            unsigned long long* __restrict__ mwT,
                                            _Float16* __restrict__ xhT2,
                                            float* __restrict__ asrc,
                                            unsigned* __restrict__ aFp_g,
                                            unsigned* __restrict__ aFm_g,
                                            float* __restrict__ admax) {
    __shared__ __align__(16) char smem[65536];        // proj B-tile / mask scratch
    const int tid = threadIdx.x;
    const int bi = blockIdx.x;
    const int r3 = bi % 3;

    if (r3 != 2) {                        // ---- mask pack, transposed [b][c][n]
        unsigned long long (*mwt)[4] = (unsigned long long (*)[4])smem;
        const int mid = (bi / 3) * 2 + r3;             // 0..1023
        const int w = tid >> 6, lane = tid & 63;
        const int b = mid >> 9, n0 = (mid & 511) * 4;
        const int* Arow = A + ((size_t)b * NN + n0 + w) * NN + lane;
        int v[32];
#pragma unroll
        for (int c = 0; c < 32; ++c) v[c] = Arow[c * 64];
#pragma unroll
        for (int c = 0; c < 32; ++c) {
            unsigned long long m = __ballot(v[c] != 0);
            if (lane == 0) mwt[c][w] = m;
        }
        __syncthreads();
        if (tid < 128) {
            const int c = tid >> 2, rl = tid & 3;
            mwT[((size_t)b * 32 + c) * NN + n0 + rl] = mwt[c][rl];
        }
        return;
    }

    // ---- proj GEMM block
    _Float16* bt = (_Float16*)smem;                    // 64 KB B tile
    const int pid = bi / 3;                            // 0..511
    const int mtile = pid >> 3, h = pid & 7;
    const int m0 = mtile * 64;
    {
        const int cir = tid & 63, wv4 = tid >> 6;
        const char* gsrc = (const char*)(WT + (size_t)h * 64 * DD);
        char* lbase = (char*)bt;
#pragma unroll
        for (int q = 0; q < 16; ++q) {
            const int row = q * 4 + wv4;
            *(uint4*)(lbase + row * 1024 + ((cir ^ (row & 7)) * 16)) =
                *(const uint4*)(gsrc + (size_t)row * 1024 + cir * 16);
        }
    }
    __syncthreads();
    const int w = tid >> 6, l = tid & 63, li = l & 15, p = l >> 4;
    const char* bbase = (const char*)bt;
    const _Float16* abase = x16t + ((size_t)(mtile * 4 + w)) * 64 * 128 + li * 8;
    floatx4 acc[4] = {};
    for (int k0 = 0; k0 < DD; k0 += 32) {
        const int ch = (k0 >> 3) + p;
        half8 a = *(const half8*)(abase + (size_t)ch * 128);
#pragma unroll
        for (int ct = 0; ct < 4; ++ct) {
            const int row = ct * 16 + li;
            half8 bfr = *(const half8*)(bbase + row * 1024 + ((ch ^ (li & 7)) * 16));
            acc[ct] = __builtin_amdgcn_mfma_f32_16x16x32_f16(a, bfr, acc[ct], 0, 0, 0);
        }
    }
    const int b = m0 >> 11, n0m = m0 & (NN - 1);
    const int c = n0m >> 6;
    const int bh = b * HH + h;
    // xhT2 tile write, PLAIN layout: byte = kk*128 + j*2, j = w*16 + p*4 + r
    {
        char* tb2 = (char*)xhT2 + ((size_t)(bh * 32 + c)) * 8192;
#pragma unroll
        for (int ct = 0; ct < 4; ++ct) {
            const int kk = ct * 16 + li;
            half4 hv;
#pragma unroll
            for (int r = 0; r < 4; ++r) hv[r] = (_Float16)acc[ct][r];
            *(half4*)(tb2 + kk * 128 + w * 32 + p * 8) = hv;
        }
    }
    float w1[4], w2[4];
#pragma unroll
    for (int ct = 0; ct < 4; ++ct) {
        w1[ct] = Watt[h * 128 + ct * 16 + li];
        w2[ct] = Watt[h * 128 + 64 + ct * 16 + li];
    }
    float s1v[4], s2v[4];
    float mx = -1e30f;
#pragma unroll
    for (int r = 0; r < 4; ++r) {
        float s1 = 0.f, s2 = 0.f;
#pragma unroll
        for (int ct = 0; ct < 4; ++ct) { s1 += acc[ct][r] * w1[ct]; s2 += acc[ct][r] * w2[ct]; }
#pragma unroll
        for (int d = 1; d < 16; d <<= 1) { s1 += __shfl_xor(s1, d, 64); s2 += __shfl_xor(s2, d, 64); }
        s1v[r] = s1; s2v[r] = s2;
        mx = fmaxf(mx, s2);
    }
    mx = fmaxf(mx, __shfl_xor(mx, 16, 64));
    mx = fmaxf(mx, __shfl_xor(mx, 32, 64));
    if (l == 0) admax[bh * 128 + (mtile & 31) * 4 + w] = mx;
    if (li == 0) {
        const int nb = n0m + w * 16 + p * 4;
        *(float4*)&asrc[bh * NN + nb] = make_float4(s1v[0], s1v[1], s1v[2], s1v[3]);
        union { half2v h; unsigned u; } q;
        unsigned fpw[2], fmw[2];
#pragma unroll
        for (int pr = 0; pr < 2; ++pr) {
            q.h[0] = (_Float16)exp2f(s2v[2 * pr] * LOG2E);
            q.h[1] = (_Float16)exp2f(s2v[2 * pr + 1] * LOG2E);
            fpw[pr] = q.u;
            q.h[0] = (_Float16)exp2f(NEG_SLOPE * s2v[2 * pr] * LOG2E);
            q.h[1] = (_Float16)exp2f(NEG_SLOPE * s2v[2 * pr + 1] * LOG2E);
            fmw[pr] = q.u;
        }
        const int wb = (bh * NN + nb) >> 1;
        *(uint2*)&aFp_g[wb] = make_uint2(fpw[0], fpw[1]);
        *(uint2*)&aFm_g[wb] = make_uint2(fmw[0], fmw[1]);
    }
}

// ---------------- Kernel 2: masked softmax + PV via MFMA, BARRIER-FREE loop ---
// 256 thr / 4 waves, 32-row i-tile, grid 1024. Wave g = w handles c ≡ g (mod 4),
// covering ALL 32 rows via two A-frags. V B-frags read DIRECTLY from L2-resident
// xhT2 (no LDS, no GLL, no barriers in the loop -> compiler pipelines freely).
// XCD-chunk swizzle keeps each bh's 64 blocks on one XCD's L2.
__global__ __launch_bounds__(256) void k_attn(const _Float16* __restrict__ xhT2,
                                              const float* __restrict__ asrc,
                                              const unsigned* __restrict__ aFp,
                                              const unsigned* __restrict__ aFm,
                                              const float* __restrict__ admax,
                                              const unsigned long long* __restrict__ mwT,
                                              const float* __restrict__ batt,
                                              float* __restrict__ out) {
    __shared__ float accs[3][32][64];     // 24 KB combine slots
    __shared__ float accd_s[3][32];
    __shared__ float amx_s;

    const int tid = threadIdx.x;
    const int w = tid >> 6, l = tid & 63, li = l & 15, p = l >> 4;
    const int g = w;                       // c-parity (mod 4)
    const int lb = ((blockIdx.x & 7) << 7) | (blockIdx.x >> 3);  // bijective XCD chunking
    const int bh = lb >> 6, it = lb & 63;
    const int b = bh >> 3, h = bh & (HH - 1);
    const int i0 = it * 32;

    // reduce 128 adst-max partials (wave 0)
    if (w == 0) {
        float mx = fmaxf(admax[bh * 128 + l], admax[bh * 128 + 64 + l]);
#pragma unroll
        for (int d = 1; d < 64; d <<= 1) mx = fmaxf(mx, __shfl_xor(mx, d, 64));
        if (l == 0) amx_s = mx;
    }
    __syncthreads();

    const float amL = amx_s * LOG2E;
    const float bbv = batt[h];
    const float ai0 = (asrc[bh * NN + i0 + li] + bbv) * LOG2E;        // frag-0 row
    const float ai1 = (asrc[bh * NN + i0 + 16 + li] + bbv) * LOG2E;   // frag-1 row
    const float tb0 = ai0 + amL, tb1 = ai1 + amL;
    const float Mi0 = fmaxf(tb0, NEG_SLOPE * tb0);
    const float Mi1 = fmaxf(tb1, NEG_SLOPE * tb1);
    union { half2v hh; unsigned u; } cv;
    cv.hh[0] = cv.hh[1] = (_Float16)exp2f(ai0 - Mi0);             const unsigned Ep0 = cv.u;
    cv.hh[0] = cv.hh[1] = (_Float16)exp2f(NEG_SLOPE * ai0 - Mi0); const unsigned Em0 = cv.u;
    cv.hh[0] = cv.hh[1] = (_Float16)exp2f(ai1 - Mi1);             const unsigned Ep1 = cv.u;
    cv.hh[0] = cv.hh[1] = (_Float16)exp2f(NEG_SLOPE * ai1 - Mi1); const unsigned Em1 = cv.u;

    floatx4 acc0[4] = {}, acc1[4] = {};
    floatx4 accd0 = {}, accd1 = {};
    half8 ones;
#pragma unroll
    for (int e = 0; e < 8; ++e) ones[e] = (_Float16)1.0f;

    const char* vtile = (const char*)(xhT2 + (size_t)bh * 32 * 4096);
    const unsigned long long* mwb = mwT + (size_t)b * 32 * NN + i0;
    const unsigned* fpb = aFp + bh * 1024;
    const unsigned* fmb = aFm + bh * 1024;

#pragma unroll 2
    for (int t = 0; t < 8; ++t) {
        const int c = t * 4 + g;
        const unsigned long long mw0 = mwb[(size_t)c * NN + li];
        const unsigned long long mw1 = mwb[(size_t)c * NN + 16 + li];
        const char* tb = vtile + (size_t)c * 8192;
#pragma unroll
        for (int js = 0; js < 2; ++js) {
            const uint4 Fp4 = *(const uint4*)&fpb[c * 32 + js * 16 + p * 4];
            const uint4 Fm4 = *(const uint4*)&fmb[c * 32 + js * 16 + p * 4];
            const unsigned m80 = (unsigned)(mw0 >> (js * 32 + p * 8)) & 0xFFu;
            const unsigned m81 = (unsigned)(mw1 >> (js * 32 + p * 8)) & 0xFFu;
            const unsigned fpv[4] = {Fp4.x, Fp4.y, Fp4.z, Fp4.w};
            const unsigned fmv[4] = {Fm4.x, Fm4.y, Fm4.z, Fm4.w};
            union { unsigned u[4]; half8 h; } af0u, af1u;
#pragma unroll
            for (int pi = 0; pi < 4; ++pi) {
                const unsigned m2a = (m80 >> (2 * pi)) & 3u;
                const unsigned mka = ((m2a & 1u) ? 0x0000FFFFu : 0u) |
                                     ((m2a & 2u) ? 0xFFFF0000u : 0u);
                af0u.u[pi] = pkmm(Ep0, fpv[pi], Em0, fmv[pi]) & mka;
                const unsigned m2b = (m81 >> (2 * pi)) & 3u;
                const unsigned mkb = ((m2b & 1u) ? 0x0000FFFFu : 0u) |
                                     ((m2b & 2u) ? 0xFFFF0000u : 0u);
                af1u.u[pi] = pkmm(Ep1, fpv[pi], Em1, fmv[pi]) & mkb;
            }
            const half8 af0 = af0u.h, af1 = af1u.h;
            accd0 = __builtin_amdgcn_mfma_f32_16x16x32_f16(af0, ones, accd0, 0, 0, 0);
            accd1 = __builtin_amdgcn_mfma_f32_16x16x32_f16(af1, ones, accd1, 0, 0, 0);
#pragma unroll
            for (int ct = 0; ct < 4; ++ct) {
                const half8 bf = *(const half8*)(tb + (ct * 16 + li) * 128 + js * 64 + p * 16);
                acc0[ct] = __builtin_amdgcn_mfma_f32_16x16x32_f16(af0, bf, acc0[ct], 0, 0, 0);
                acc1[ct] = __builtin_amdgcn_mfma_f32_16x16x32_f16(af1, bf, acc1[ct], 0, 0, 0);
            }
        }
    }

    // ---- combine the 4 parities: waves 1..3 -> LDS slots, wave 0 sums + writes
    if (g != 0) {
        const int s = g - 1;
#pragma unroll
        for (int ct = 0; ct < 4; ++ct)
#pragma unroll
            for (int r = 0; r < 4; ++r) {
                accs[s][p * 4 + r][ct * 16 + li] = acc0[ct][r];
                accs[s][16 + p * 4 + r][ct * 16 + li] = acc1[ct][r];
            }
        if (li == 0) {
#pragma unroll
            for (int r = 0; r < 4; ++r) {
                accd_s[s][p * 4 + r] = accd0[r];
                accd_s[s][16 + p * 4 + r] = accd1[r];
            }
        }
    }
    __syncthreads();
    if (g == 0) {
#pragma unroll
        for (int f = 0; f < 2; ++f) {
#pragma unroll
            for (int r = 0; r < 4; ++r) {
                const int row = f * 16 + p * 4 + r;
                float d = (f ? accd1[r] : accd0[r]) +
                          accd_s[0][row] + accd_s[1][row] + accd_s[2][row];
                const float inv = 1.f / fmaxf(d, 1e-30f);
                float* orow = out + ((size_t)b * NN + i0 + row) * DD + h * KK;
                const floatx4* accf = f ? acc1 : acc0;
#pragma unroll
                for (int ct = 0; ct < 4; ++ct) {
                    const int col = ct * 16 + li;
                    const float v = (accf[ct][r] + accs[0][row][col] +
                                     accs[1][row][col] + accs[2][row][col]) * inv;
                    orow[col] = fmaxf(v, 0.f);
                }
            }
        }
    }
}

extern "C" void kernel_launch(void* const* d_in, const int* in_sizes, int n_in,
                              void* d_out, int out_size, void* d_ws, size_t ws_size,
                              hipStream_t stream) {
    const float* x    = (const float*)d_in[0];
    const int*   A    = (const int*)d_in[1];
    const float* Wp   = (const float*)d_in[2];
    const float* Watt = (const float*)d_in[3];
    const float* batt = (const float*)d_in[4];
    float* out = (float*)d_out;

    char* ws = (char*)d_ws;
    _Float16* x16t = (_Float16*)(ws + X16T_OFF);
    _Float16* WT   = (_Float16*)(ws + WT_OFF);
    _Float16* xhT2 = (_Float16*)(ws + XHT_OFF);
    float* asrc  = (float*)(ws + ASRC_OFF);
    unsigned* aFp = (unsigned*)(ws + AFP_OFF);
    unsigned* aFm = (unsigned*)(ws + AFM_OFF);
    float* admax = (float*)(ws + ADMAX_OFF);
    unsigned long long* mwT = (unsigned long long*)(ws + MW_OFF);

    k_prep<<<dim3(320), 256, 0, stream>>>(x, Wp, x16t, WT);
    k_pj<<<dim3(1536), 256, 0, stream>>>(A, x16t, WT, Watt, mwT, xhT2, asrc, aFp, aFm, admax);
    k_attn<<<dim3(BB * HH * 64), 256, 0, stream>>>(xhT2, asrc, aFp, aFm, admax, mwT, batt, out);
}

// Round 15
// 50.178 us; speedup vs baseline: 1.5686x; 1.5686x over previous
//
#include <hip/hip_runtime.h>
#include <cstdint>
#include <cstddef>

#define NEG_SLOPE 0.2f
#define LOG2E 1.4426950408889634f

// Problem sizes (fixed by setup_inputs)
#define BB 2
#define NN 2048
#define DD 512
#define HH 8
#define KK 64   // head dim

typedef _Float16 half8 __attribute__((ext_vector_type(8)));
typedef _Float16 half4 __attribute__((ext_vector_type(4)));
typedef _Float16 half2v __attribute__((ext_vector_type(2)));
typedef float floatx4 __attribute__((ext_vector_type(4)));

// Workspace layout (bytes)
#define X16T_OFF  ((size_t)0)            // x16 tiled: [256 mtile][64 chunk][16 m][8 k] f16 = 4 MB
#define WT_OFF    ((size_t)4194304)      // WT[o][d] f16 = 512 KB
#define XHT_OFF   ((size_t)4718592)      // xhT2: [B*H][32 c][64 kk][64 j] f16 (pre-swizzled) = 4 MB
#define ASRC_OFF  ((size_t)8912896)      // 32768 f32 = 128 KB
#define AF_OFF    ((size_t)9043968)      // aF: [bh][n] half2-packed u32 = 128 KB
#define ADMAX_OFF ((size_t)9175040)      // [16 bh][128] f32 = 8 KB
#define MW_OFF    ((size_t)9183232)      // mwT: [B][32][2048] u64 = 1 MB

// async global->LDS, 16B per lane; lbase is wave-uniform, lane writes lbase+lane*16
#if __has_builtin(__builtin_amdgcn_global_load_lds)
#define GLL(gsrc, lbase, lane) \
    __builtin_amdgcn_global_load_lds((const __attribute__((address_space(1))) void*)(gsrc), \
                                     (__attribute__((address_space(3))) void*)(lbase), 16, 0, 0)
#else
#define GLL(gsrc, lbase, lane) \
    (*(uint4*)((char*)(lbase) + (size_t)(lane) * 16) = *(const uint4*)(gsrc))
#endif

// ---------------- Kernel 0: mask pack + x->f16 tiled + W transpose ------------
// One grid: blocks [0,1024) mask, [1024,1280) x-convert, [1280,1344) W-transpose.
__global__ __launch_bounds__(256) void k_pm(const int* __restrict__ A,
                                            const float* __restrict__ x,
                                            const float* __restrict__ Wp,
                                            unsigned long long* __restrict__ mwT,
                                            _Float16* __restrict__ x16t,
                                            _Float16* __restrict__ WT) {
    __shared__ float tile[64][65];
    __shared__ unsigned long long mwt[32][4];
    const int tid = threadIdx.x;
    const int bi = blockIdx.x;
    if (bi < 1024) {                      // ---- mask pack, transposed [b][c][n]
        const int w = tid >> 6, lane = tid & 63;
        const int b = bi >> 9, n0 = (bi & 511) * 4;
        const int* Arow = A + ((size_t)b * NN + n0 + w) * NN + lane;
        int v[32];
#pragma unroll
        for (int c = 0; c < 32; ++c) v[c] = Arow[c * 64];
#pragma unroll
        for (int c = 0; c < 32; ++c) {
            unsigned long long m = __ballot(v[c] != 0);
            if (lane == 0) mwt[c][w] = m;
        }
        __syncthreads();
        if (tid < 128) {
            const int c = tid >> 2, rl = tid & 3;
            mwT[((size_t)b * 32 + c) * NN + n0 + rl] = mwt[c][rl];
        }
    } else if (bi < 1280) {               // ---- x conversion to tiled layout
        const int xb = bi - 1024;
        const int r = tid & 15, cg = tid >> 4;
        const float* srow = x + (size_t)(xb * 16 + r) * DD;
        _Float16* obase = x16t + ((size_t)xb * 64) * 128 + r * 8;
#pragma unroll
        for (int q = 0; q < 4; ++q) {
            const int chunk = q * 16 + cg;
            float4 v0 = *(const float4*)(srow + chunk * 8);
            float4 v1 = *(const float4*)(srow + chunk * 8 + 4);
            half8 hv;
            hv[0] = (_Float16)v0.x; hv[1] = (_Float16)v0.y;
            hv[2] = (_Float16)v0.z; hv[3] = (_Float16)v0.w;
            hv[4] = (_Float16)v1.x; hv[5] = (_Float16)v1.y;
            hv[6] = (_Float16)v1.z; hv[7] = (_Float16)v1.w;
            *(half8*)(obase + (size_t)chunk * 128) = hv;
        }
    } else {                              // ---- W transpose: 64 blocks of 64x64
        const int wb = bi - 1280;
        const int d0 = (wb >> 3) * 64, o0 = (wb & 7) * 64;
        const int r = tid >> 2, cq = tid & 3;
#pragma unroll
        for (int qq = 0; qq < 4; ++qq) {
            float4 v = *(const float4*)&Wp[(size_t)(d0 + r) * DD + o0 + cq * 16 + qq * 4];
            tile[r][cq * 16 + qq * 4 + 0] = v.x;
            tile[r][cq * 16 + qq * 4 + 1] = v.y;
            tile[r][cq * 16 + qq * 4 + 2] = v.z;
            tile[r][cq * 16 + qq * 4 + 3] = v.w;
        }
        __syncthreads();
#pragma unroll
        for (int qq = 0; qq < 2; ++qq) {
            half8 hv;
#pragma unroll
            for (int e = 0; e < 8; ++e) hv[e] = (_Float16)tile[cq * 16 + qq * 8 + e][r];
            *(half8*)&WT[(size_t)(o0 + r) * DD + d0 + cq * 16 + qq * 8] = hv;
        }
    }
}

// ---------------- Kernel 1: proj GEMM (f16 MFMA, B in swizzled LDS) -----------
// Grid 512 (64 m-tiles x 8 heads), 256 thr / 4 waves; wave owns 16 rows x 64 cols.
// Epilogue: xhT2 (attn-swizzle baked in), asrc, packed F-pairs, adst-max partials.
__global__ __launch_bounds__(256) void k_proj(const _Float16* __restrict__ x16t,
                                              const _Float16* __restrict__ WT,
                                              const float* __restrict__ Watt,
                                              _Float16* __restrict__ xhT2,
                                              float* __restrict__ asrc,
                                              unsigned* __restrict__ aFg,
                                              float* __restrict__ admax) {
    __shared__ __align__(16) _Float16 bt[64 * 512];   // 64 KB
    const int tid = threadIdx.x;
    const int bi = blockIdx.x;
    const int mtile = bi >> 3, h = bi & 7;
    const int m0 = mtile * 64;
    // stage B: row = q*4 + wave, 1KB per row, chunk XOR (row&7)
    {
        const int cir = tid & 63, wv4 = tid >> 6;
        const char* gsrc = (const char*)(WT + (size_t)h * 64 * DD);
        char* lbase = (char*)bt;
#pragma unroll
        for (int q = 0; q < 16; ++q) {
            const int row = q * 4 + wv4;
            *(uint4*)(lbase + row * 1024 + ((cir ^ (row & 7)) * 16)) =
                *(const uint4*)(gsrc + (size_t)row * 1024 + cir * 16);
        }
    }
    __syncthreads();
    const int w = tid >> 6, l = tid & 63, li = l & 15, p = l >> 4;
    const char* bbase = (const char*)bt;
    const _Float16* abase = x16t + ((size_t)(mtile * 4 + w)) * 64 * 128 + li * 8;
    floatx4 acc[4] = {};
    for (int k0 = 0; k0 < DD; k0 += 32) {
        const int ch = (k0 >> 3) + p;
        half8 a = *(const half8*)(abase + (size_t)ch * 128);
#pragma unroll
        for (int ct = 0; ct < 4; ++ct) {
            const int row = ct * 16 + li;
            half8 bfr = *(const half8*)(bbase + row * 1024 + ((ch ^ (li & 7)) * 16));
            acc[ct] = __builtin_amdgcn_mfma_f32_16x16x32_f16(a, bfr, acc[ct], 0, 0, 0);
        }
    }
    const int b = m0 >> 11, n0m = m0 & (NN - 1);
    const int c = n0m >> 6;
    const int bh = b * HH + h;
    // xhT2 tile write, swizzle baked in: byte = kk*128 + ((colchunk^(kk&7))<<4) + (col&7)*2
    {
        char* tb2 = (char*)xhT2 + ((size_t)(bh * 32 + c)) * 8192;
        const int colchunk = w * 2 + (p >> 1);
        const int sub = (p & 1) * 8;
#pragma unroll
        for (int ct = 0; ct < 4; ++ct) {
            const int kk = ct * 16 + li;
            half4 hv;
#pragma unroll
            for (int r = 0; r < 4; ++r) hv[r] = (_Float16)acc[ct][r];
            *(half4*)(tb2 + kk * 128 + ((colchunk ^ (kk & 7)) << 4) + sub) = hv;
        }
    }
    // fused a_src / F-pair + per-wave adst max partial
    float w1[4], w2[4];
#pragma unroll
    for (int ct = 0; ct < 4; ++ct) {
        w1[ct] = Watt[h * 128 + ct * 16 + li];
        w2[ct] = Watt[h * 128 + 64 + ct * 16 + li];
    }
    float mx = -1e30f;
#pragma unroll
    for (int r = 0; r < 4; ++r) {
        float s1 = 0.f, s2 = 0.f;
#pragma unroll
        for (int ct = 0; ct < 4; ++ct) { s1 += acc[ct][r] * w1[ct]; s2 += acc[ct][r] * w2[ct]; }
#pragma unroll
        for (int d = 1; d < 16; d <<= 1) { s1 += __shfl_xor(s1, d, 64); s2 += __shfl_xor(s2, d, 64); }
        mx = fmaxf(mx, s2);
        if (li == 0) {
            const int n = n0m + w * 16 + p * 4 + r;
            asrc[bh * NN + n] = s1;
            const float bj = s2 * LOG2E;
            union { half2v h; unsigned u; } cv;
            cv.h[0] = (_Float16)exp2f(bj);            // F+ = 2^bj
            cv.h[1] = (_Float16)exp2f(NEG_SLOPE * bj);// F- = 2^(0.2 bj)
            aFg[bh * NN + n] = cv.u;
        }
    }
    mx = fmaxf(mx, __shfl_xor(mx, 16, 64));
    mx = fmaxf(mx, __shfl_xor(mx, 32, 64));
    if (l == 0) admax[bh * 128 + (mtile & 31) * 4 + w] = mx;
}

// ---------------- Kernel 2: masked softmax + PV via MFMA ----------------------
// 256 thr / 4 waves, 32-row i-tile, grid 1024. Wave w: parity g=w&1 (c mod 2),
// row-half wr=w>>1. V tiles double-buffered via global_load_lds.
// Scores via rank-1 factored exp: w = max(E+·F+, E-·F-) — no exp in inner loop.
// T5: setprio(1) around the MFMA cluster (4 independent blocks/CU -> phase split).
__global__ __launch_bounds__(256) void k_attn(const _Float16* __restrict__ xhT2,
                                              const float* __restrict__ asrc,
                                              const unsigned* __restrict__ aFg,
                                              const float* __restrict__ admax,
                                              const unsigned long long* __restrict__ mwT,
                                              const float* __restrict__ batt,
                                              float* __restrict__ out) {
    __shared__ __align__(16) _Float16 vt[2][2][4096];     // [parity][buf][8KB]
    __shared__ __align__(16) unsigned aFl[2][2][64];      // packed F-pairs
    __shared__ unsigned long long mwl[2][2][32];
    __shared__ float accd_s[2][16];
    __shared__ float amx_s;

    const int tid = threadIdx.x;
    const int w = tid >> 6, l = tid & 63, li = l & 15, p = l >> 4;
    const int g = w & 1, wr = w >> 1;
    const int bid = blockIdx.x;
    const int bh = bid >> 6, it = bid & 63;
    const int b = bh >> 3, h = bh & (HH - 1);
    const int i0 = it * 32;

    const _Float16* vbase = xhT2 + (size_t)bh * 32 * 4096;  // tile = 4096 halves

    // ---- prologue: stage tile pair ci=0 (c = parity) into buf 0
    {
#pragma unroll
        for (int q = 0; q < 4; ++q) {
            const int chunk = (wr * 4 + q) * 64 + l;       // 16B chunk index in tile
            GLL(vbase + (size_t)g * 4096 + chunk * 8, &vt[g][0][(wr * 4 + q) * 512], l);
        }
        if (tid < 128) aFl[tid >> 6][0][tid & 63] =
            aFg[bh * NN + (tid >> 6) * 64 + (tid & 63)];
        if (tid < 64) mwl[tid >> 5][0][tid & 31] =
            mwT[((size_t)b * 32 + (tid >> 5)) * NN + i0 + (tid & 31)];
    }
    // reduce 128 adst-max partials (wave 0)
    if (w == 0) {
        float mx = fmaxf(admax[bh * 128 + l], admax[bh * 128 + 64 + l]);
#pragma unroll
        for (int d = 1; d < 64; d <<= 1) mx = fmaxf(mx, __shfl_xor(mx, d, 64));
        if (l == 0) amx_s = mx;
    }
    __syncthreads();   // drains GLL (vmcnt) + LDS writes; amx_s visible

    const float am = amx_s;
    const float bbv = batt[h];
    const int i = i0 + wr * 16 + li;
    const float ai = (asrc[bh * NN + i] + bbv) * LOG2E;    // log2-domain src score
    const float tb = ai + am * LOG2E;
    const float Mi = fmaxf(tb, NEG_SLOPE * tb);            // row-max upper bound
    half2v eh2;
    eh2[0] = (_Float16)exp2f(ai - Mi);                     // E+
    eh2[1] = (_Float16)exp2f(NEG_SLOPE * ai - Mi);         // E-
    floatx4 acc[4] = {};
    floatx4 accd = {};
    half8 ones;
#pragma unroll
    for (int e = 0; e < 8; ++e) ones[e] = (_Float16)1.0f;

    unsigned raF = 0; unsigned long long rmw = 0;
    for (int ci = 0; ci < 16; ++ci) {
        const int buf = ci & 1;
        char* vtg = (char*)&vt[g][buf][0];
        // issue next tile's loads (fly during compute below)
        if (ci < 15) {
            const int cn = 2 * (ci + 1) + g;
#pragma unroll
            for (int q = 0; q < 4; ++q) {
                const int chunk = (wr * 4 + q) * 64 + l;
                GLL(vbase + (size_t)cn * 4096 + chunk * 8, &vt[g][buf ^ 1][(wr * 4 + q) * 512], l);
            }
            if (tid < 128) raF = aFg[bh * NN + (2 * (ci + 1) + (tid >> 6)) * 64 + (tid & 63)];
            if (tid < 64)  rmw = mwT[((size_t)b * 32 + 2 * (ci + 1) + (tid >> 5)) * NN + i0 + (tid & 31)];
        }
        // compute current tile
        const unsigned long long mword = mwl[g][buf][wr * 16 + li];
#pragma unroll
        for (int js = 0; js < 2; ++js) {
            const int shbase = js * 32 + p * 8;
            uint4 F0 = *(const uint4*)&aFl[g][buf][shbase];
            uint4 F1 = *(const uint4*)&aFl[g][buf][shbase + 4];
            const unsigned m8 = (unsigned)(mword >> shbase) & 0xFFu;
            unsigned fb[8] = {F0.x, F0.y, F0.z, F0.w, F1.x, F1.y, F1.z, F1.w};
            half8 af;
#pragma unroll
            for (int e = 0; e < 8; ++e) {
                union { unsigned u; half2v h; } cv; cv.u = fb[e];
                half2v em = eh2 * cv.h;                    // v_pk_mul_f16: both branches
                _Float16 wv = em[0] > em[1] ? em[0] : em[1];
                af[e] = ((m8 >> e) & 1u) ? wv : (_Float16)0.f;
            }
            __builtin_amdgcn_s_setprio(1);                 // T5: favor MFMA-entering wave
            accd = __builtin_amdgcn_mfma_f32_16x16x32_f16(af, ones, accd, 0, 0, 0);
#pragma unroll
            for (int ct = 0; ct < 4; ++ct) {
                const half8 bf = *(const half8*)(vtg + (ct * 16 + li) * 128 +
                                                 (((js * 4 + p) ^ (li & 7)) << 4));
                acc[ct] = __builtin_amdgcn_mfma_f32_16x16x32_f16(af, bf, acc[ct], 0, 0, 0);
            }
            __builtin_amdgcn_s_setprio(0);
        }
        // commit next tile's small state, then single barrier
        if (ci < 15) {
            if (tid < 128) aFl[tid >> 6][buf ^ 1][tid & 63] = raF;
            if (tid < 64)  mwl[tid >> 5][buf ^ 1][tid & 31] = rmw;
        }
        __syncthreads();
    }

    // combine the two c-parities (pair = waves with same wr) via LDS
    float* accs = (float*)&vt[0][0][0];    // 8 KB: [32 rows][64 cols]
    if (g == 1) {
#pragma unroll
        for (int ct = 0; ct < 4; ++ct)
#pragma unroll
            for (int r = 0; r < 4; ++r)
                accs[(wr * 16 + p * 4 + r) * 64 + ct * 16 + li] = acc[ct][r];
        if (li == 0) {
#pragma unroll
            for (int r = 0; r < 4; ++r) accd_s[wr][p * 4 + r] = accd[r];
        }
    }
    __syncthreads();
    if (g == 0) {
#pragma unroll
        for (int r = 0; r < 4; ++r) {
            const float d = accd[r] + accd_s[wr][p * 4 + r];
            const float inv = 1.f / fmaxf(d, 1e-30f);
            const int irow = i0 + wr * 16 + p * 4 + r;
            float* orow = out + ((size_t)b * NN + irow) * DD + h * KK;
#pragma unroll
            for (int ct = 0; ct < 4; ++ct) {
                const float v = (acc[ct][r] + accs[(wr * 16 + p * 4 + r) * 64 + ct * 16 + li]) * inv;
                orow[ct * 16 + li] = fmaxf(v, 0.f);
            }
        }
    }
}

extern "C" void kernel_launch(void* const* d_in, const int* in_sizes, int n_in,
                              void* d_out, int out_size, void* d_ws, size_t ws_size,
                              hipStream_t stream) {
    const float* x    = (const float*)d_in[0];
    const int*   A    = (const int*)d_in[1];
    const float* Wp   = (const float*)d_in[2];
    const float* Watt = (const float*)d_in[3];
    const float* batt = (const float*)d_in[4];
    float* out = (float*)d_out;

    char* ws = (char*)d_ws;
    _Float16* x16t = (_Float16*)(ws + X16T_OFF);
    _Float16* WT   = (_Float16*)(ws + WT_OFF);
    _Float16* xhT2 = (_Float16*)(ws + XHT_OFF);
    float* asrc  = (float*)(ws + ASRC_OFF);
    unsigned* aFg = (unsigned*)(ws + AF_OFF);
    float* admax = (float*)(ws + ADMAX_OFF);
    unsigned long long* mwT = (unsigned long long*)(ws + MW_OFF);

    k_pm<<<dim3(1344), 256, 0, stream>>>(A, x, Wp, mwT, x16t, WT);
    k_proj<<<dim3(512), 256, 0, stream>>>(x16t, WT, Watt, xhT2, asrc, aFg, admax);
    k_attn<<<dim3(BB * HH * 64), 256, 0, stream>>>(xhT2, asrc, aFg, admax, mwT, batt, out);
}